// Round 1
// baseline (11985.731 us; speedup 1.0000x reference)
//
#include <hip/hip_runtime.h>

#define D   2048
#define S   2048
#define NQ  16384
#define DD  ((long)D * (long)D)

// ---- ws layout (float indices) ----
#define IDX_N      0        // [2] class counts (atomic)
#define IDX_NORMS  16       // [2][16] power-iter norms (atomic)
#define IDX_S      48       // [2] mu^T P mu
#define IDX_SUM    256      // [2][2048] masked column sums (atomic)
#define IDX_MU     4608     // [2][2048] class means
#define IDX_MUF    8704     // [2048]   full mean
#define IDX_U      10752    // [2][2048] u = P mu
#define IDX_V      14848    // [2][2048] power vec ping
#define IDX_W2     18944    // [2][2048] power vec pong
#define IDX_ACC    32768    // [16384][2] logits accumulator (atomic)
#define SMALL_FLOATS 65536  // 256 KB zeroed region

#define NPOW 12
#define NNS  9

// ---------------- small kernels ----------------

__global__ void k_counts(const int* __restrict__ lab, float* __restrict__ W) {
    int c0 = 0, c1 = 0;
    for (int i = threadIdx.x; i < S; i += 256) {
        int l = lab[i];
        c0 += (l == 0);
        c1 += (l == 1);
    }
    atomicAdd(&W[IDX_N + 0], (float)c0);
    atomicAdd(&W[IDX_N + 1], (float)c1);
}

__global__ void k_colsums(const float* __restrict__ X, const int* __restrict__ lab,
                          float* __restrict__ W) {
    int d  = blockIdx.x * 256 + threadIdx.x;   // column
    int i0 = blockIdx.y * 128;                 // row chunk
    float s0 = 0.f, s1 = 0.f;
    for (int i = i0; i < i0 + 128; ++i) {
        float v = X[(long)i * D + d];
        int   l = lab[i];
        s0 += (l == 0) ? v : 0.f;
        s1 += (l == 1) ? v : 0.f;
    }
    atomicAdd(&W[IDX_SUM + d],     s0);
    atomicAdd(&W[IDX_SUM + D + d], s1);
}

__global__ void k_stats(float* __restrict__ W) {
    int d = blockIdx.x * 256 + threadIdx.x;    // 8 blocks x 256 = 2048
    float n0 = W[IDX_N], n1 = W[IDX_N + 1];
    float s0 = W[IDX_SUM + d], s1 = W[IDX_SUM + D + d];
    W[IDX_MU + d]     = s0 / n0;
    W[IDX_MU + D + d] = s1 / n1;
    W[IDX_MUF + d]    = (s0 + s1) / (float)S;
    unsigned h = (unsigned)d * 2654435761u;
    float r = 0.5f + (float)((h >> 16) & 1023) / 1024.f;  // power-iter seed
    W[IDX_V + d]     = r;
    W[IDX_V + D + d] = r;
}

// Build M_c = lam*cov_c + (1-lam)*task_cov + 0.1 I, in place over the Gram buffers.
__global__ void k_build_M(float* __restrict__ AM, const float* __restrict__ W) {
    long idx = (long)blockIdx.x * 256 + threadIdx.x;   // < DD
    int d = (int)(idx / D), e = (int)(idx % D);
    float n0 = W[IDX_N], n1 = W[IDX_N + 1];
    float mufd = W[IDX_MUF + d],     mufe = W[IDX_MUF + e];
    float m0d  = W[IDX_MU + d],      m0e  = W[IDX_MU + e];
    float m1d  = W[IDX_MU + D + d],  m1e  = W[IDX_MU + D + e];
    float a0 = AM[idx], a1 = AM[DD + idx];
    float task = (a0 + a1 - (float)S * mufd * mufe) * (1.f / (float)(S - 1));
    float c0 = (a0 - n0 * m0d * m0e) / (n0 - 1.f);
    float c1 = (a1 - n1 * m1d * m1e) / (n1 - 1.f);
    float l0 = fminf(n0 / (n0 + 1.f), 0.1f);
    float l1 = fminf(n1 / (n1 + 1.f), 0.1f);
    float eye = (d == e) ? 0.1f : 0.f;
    AM[idx]      = l0 * c0 + (1.f - l0) * task + eye;
    AM[DD + idx] = l1 * c1 + (1.f - l1) * task + eye;
}

// Power iteration step: out = M * in * scale ; norms[it] += ||out||^2
__global__ void k_pow(const float* __restrict__ Mm, float* __restrict__ W, int it) {
    int z = blockIdx.y;
    const float* Mz = Mm + (long)z * DD;
    float* V  = W + IDX_V  + z * D;
    float* W2 = W + IDX_W2 + z * D;
    const float* in = (it & 1) ? W2 : V;
    float*       out = (it & 1) ? V  : W2;
    float sc = (it > 0) ? rsqrtf(W[IDX_NORMS + z * 16 + it - 1]) : 1.f;
    int wv = threadIdx.x >> 6, ln = threadIdx.x & 63;
    int d = blockIdx.x * 4 + wv;
    float p = 0.f;
    for (int e = ln; e < D; e += 64) p += Mz[(long)d * D + e] * in[e];
    for (int off = 32; off; off >>= 1) p += __shfl_down(p, off);
    if (ln == 0) {
        float w = p * sc;
        out[d] = w;
        atomicAdd(&W[IDX_NORMS + z * 16 + it], w * w);
    }
}

// X0 = alpha * I with alpha = 2/(0.1 + 1.25*lambda_max_hat + 0.05)
__global__ void k_init_X(float* __restrict__ X, const float* __restrict__ W) {
    long idx = (long)blockIdx.x * 256 + threadIdx.x;   // < 2*DD
    int z = (int)(idx / DD);
    long r = idx - (long)z * DD;
    int d = (int)(r / D), e = (int)(r % D);
    float lam = sqrtf(W[IDX_NORMS + z * 16 + (NPOW - 1)]);
    float lmax = 1.25f * lam + 0.05f;
    float a = 2.f / (0.1f + lmax);
    X[idx] = (d == e) ? a : 0.f;
}

// u = P * mu
__global__ void k_matvec_u(const float* __restrict__ P, float* __restrict__ W) {
    int z = blockIdx.y;
    const float* Pz = P + (long)z * DD;
    const float* mu = W + IDX_MU + z * D;
    int wv = threadIdx.x >> 6, ln = threadIdx.x & 63;
    int d = blockIdx.x * 4 + wv;
    float p = 0.f;
    for (int e = ln; e < D; e += 64) p += Pz[(long)d * D + e] * mu[e];
    for (int off = 32; off; off >>= 1) p += __shfl_down(p, off);
    if (ln == 0) W[IDX_U + z * D + d] = p;
}

// s_z = mu . u
__global__ void k_dot(float* __restrict__ W) {
    int z = blockIdx.x;
    float t = 0.f;
    for (int d = threadIdx.x; d < D; d += 256)
        t += W[IDX_MU + z * D + d] * W[IDX_U + z * D + d];
    for (int off = 32; off; off >>= 1) t += __shfl_down(t, off);
    __shared__ float sm[4];
    int wv = threadIdx.x >> 6, ln = threadIdx.x & 63;
    if (ln == 0) sm[wv] = t;
    __syncthreads();
    if (threadIdx.x == 0) W[IDX_S + z] = sm[0] + sm[1] + sm[2] + sm[3];
}

__global__ void k_finalize(const float* __restrict__ W, float* __restrict__ out) {
    int idx = blockIdx.x * 256 + threadIdx.x;   // 32768
    int z = idx & 1;
    out[idx] = -(W[IDX_ACC + idx] + W[IDX_S + z]);
}

// ---------------- GEMM ----------------
// C[m,n] = alpha * sum_k Aop[m,k] * B[k,n] + beta * E[m,n]
// TN==0: A row-major [M,K] (lda=K).  TN==1: A stored [K,M] (lda=M-leading), i.e. C = A^T B.
// MASKED: multiply A rows (k index) by (labels[k]==blockIdx.z).
// FUSE: instead of storing C, accumulate logits partials:
//       acc[n_row*2+z] += sum_cols (C - 2*u[z][col]) * Qfull[n_row, col]
template <int TN, int MASKED, int FUSE>
__global__ void __launch_bounds__(256)
gemm128(const float* __restrict__ A, const float* __restrict__ B,
        float* __restrict__ C, const float* __restrict__ E,
        float alpha, float beta,
        int lda, int ldb, int ldc, int K,
        long sAz, long sBz, long sCz, long sEz,
        const int* __restrict__ labels,
        const float* __restrict__ u, float* __restrict__ acc,
        const float* __restrict__ Qfull) {
    int z = blockIdx.z;
    A += (long)z * sAz;
    B += (long)z * sBz;
    if (C) C += (long)z * sCz;
    if (E) E += (long)z * sEz;

    int n0 = blockIdx.x * 128;
    int m0 = blockIdx.y * 128;
    int tid = threadIdx.x;
    int tx = tid & 15, ty = tid >> 4;

    __shared__ float As[16][128];
    __shared__ float Bs[16][128];

    float acc8[8][8];
#pragma unroll
    for (int i = 0; i < 8; ++i)
#pragma unroll
        for (int j = 0; j < 8; ++j) acc8[i][j] = 0.f;

    for (int k0 = 0; k0 < K; k0 += 16) {
        // ---- stage A ----
        if (TN == 0) {
#pragma unroll
            for (int q = 0; q < 2; ++q) {
                int fid = tid + q * 256;            // 0..511
                int m = fid >> 2, kq = (fid & 3) << 2;
                const float4 av = *(const float4*)&A[(long)(m0 + m) * lda + k0 + kq];
                As[kq + 0][m] = av.x;
                As[kq + 1][m] = av.y;
                As[kq + 2][m] = av.z;
                As[kq + 3][m] = av.w;
            }
        } else {
#pragma unroll
            for (int q = 0; q < 2; ++q) {
                int fid = tid + q * 256;
                int kk = fid >> 5, mq = (fid & 31) << 2;
                float4 av = *(const float4*)&A[(long)(k0 + kk) * lda + m0 + mq];
                if (MASKED) {
                    float w = (labels[k0 + kk] == z) ? 1.f : 0.f;
                    av.x *= w; av.y *= w; av.z *= w; av.w *= w;
                }
                *(float4*)&As[kk][mq] = av;
            }
        }
        // ---- stage B ----
#pragma unroll
        for (int q = 0; q < 2; ++q) {
            int fid = tid + q * 256;
            int kk = fid >> 5, nq = (fid & 31) << 2;
            *(float4*)&Bs[kk][nq] = *(const float4*)&B[(long)(k0 + kk) * ldb + n0 + nq];
        }
        __syncthreads();
        // ---- compute ----
#pragma unroll
        for (int kk = 0; kk < 16; ++kk) {
            float a[8], b[8];
            *(float4*)(a)     = *(float4*)&As[kk][ty * 8];
            *(float4*)(a + 4) = *(float4*)&As[kk][ty * 8 + 4];
            *(float4*)(b)     = *(float4*)&Bs[kk][tx * 8];
            *(float4*)(b + 4) = *(float4*)&Bs[kk][tx * 8 + 4];
#pragma unroll
            for (int i = 0; i < 8; ++i)
#pragma unroll
                for (int j = 0; j < 8; ++j) acc8[i][j] = fmaf(a[i], b[j], acc8[i][j]);
        }
        __syncthreads();
    }

    if (FUSE == 0) {
#pragma unroll
        for (int i = 0; i < 8; ++i) {
            int m = m0 + ty * 8 + i;
#pragma unroll
            for (int j = 0; j < 8; j += 4) {
                int n = n0 + tx * 8 + j;
                float4 v;
                v.x = alpha * acc8[i][j + 0];
                v.y = alpha * acc8[i][j + 1];
                v.z = alpha * acc8[i][j + 2];
                v.w = alpha * acc8[i][j + 3];
                if (beta != 0.f) {
                    const float4 ev = *(const float4*)&E[(long)m * ldc + n];
                    v.x += beta * ev.x; v.y += beta * ev.y;
                    v.z += beta * ev.z; v.w += beta * ev.w;
                }
                *(float4*)&C[(long)m * ldc + n] = v;
            }
        }
    } else {
#pragma unroll
        for (int i = 0; i < 8; ++i) {
            int n = m0 + ty * 8 + i;   // global query row
            float t = 0.f;
#pragma unroll
            for (int j = 0; j < 8; ++j) {
                int e = n0 + tx * 8 + j;
                t += (acc8[i][j] - 2.f * u[z * D + e]) * Qfull[(long)n * D + e];
            }
            for (int off = 8; off; off >>= 1) t += __shfl_down(t, off, 16);
            if (tx == 0) atomicAdd(&acc[n * 2 + z], t);
        }
    }
}

// ---------------- launch ----------------

extern "C" void kernel_launch(void* const* d_in, const int* in_sizes, int n_in,
                              void* d_out, int out_size, void* d_ws, size_t ws_size,
                              hipStream_t stream) {
    const float* Q   = (const float*)d_in[0];   // [16384, 2048]
    const float* Xs  = (const float*)d_in[1];   // [2048, 2048]
    const int*   lab = (const int*)d_in[2];     // [2048]
    float* out = (float*)d_out;
    float* W   = (float*)d_ws;

    float* BIG = W + SMALL_FLOATS;
    float* AM  = BIG;            // [2][D][D]  Gram -> M
    float* Xb0 = BIG + 2 * DD;   // [2][D][D]  NS ping
    float* Xb1 = BIG + 4 * DD;   // [2][D][D]  NS pong
    float* Tb  = BIG + 6 * DD;   // [2][D][D]  NS temp
    // total ws need: (SMALL_FLOATS + 8*DD)*4 bytes ~ 134.5 MB

    hipMemsetAsync(d_ws, 0, SMALL_FLOATS * sizeof(float), stream);

    k_counts<<<1, 256, 0, stream>>>(lab, W);
    k_colsums<<<dim3(D / 256, 16), 256, 0, stream>>>(Xs, lab, W);
    k_stats<<<D / 256, 256, 0, stream>>>(W);

    // Gram: AM[c] = (mask_c . X)^T X
    gemm128<1, 1, 0><<<dim3(16, 16, 2), 256, 0, stream>>>(
        Xs, Xs, AM, nullptr, 1.f, 0.f,
        D, D, D, S, 0, 0, DD, 0, lab, nullptr, nullptr, nullptr);

    k_build_M<<<(int)(DD / 256), 256, 0, stream>>>(AM, W);

    for (int it = 0; it < NPOW; ++it)
        k_pow<<<dim3(D / 4, 2), 256, 0, stream>>>(AM, W, it);

    k_init_X<<<(int)(2 * DD / 256), 256, 0, stream>>>(Xb0, W);

    float* cur = Xb0;
    float* nxt = Xb1;
    for (int it = 0; it < NNS; ++it) {
        // T = M * X
        gemm128<0, 0, 0><<<dim3(16, 16, 2), 256, 0, stream>>>(
            AM, cur, Tb, nullptr, 1.f, 0.f,
            D, D, D, D, DD, DD, DD, 0, nullptr, nullptr, nullptr, nullptr);
        // Xnext = 2X - X*T
        gemm128<0, 0, 0><<<dim3(16, 16, 2), 256, 0, stream>>>(
            cur, Tb, nxt, cur, -1.f, 2.f,
            D, D, D, D, DD, DD, DD, DD, nullptr, nullptr, nullptr, nullptr);
        float* t = cur; cur = nxt; nxt = t;
    }
    // P = cur

    k_matvec_u<<<dim3(D / 4, 2), 256, 0, stream>>>(cur, W);
    k_dot<<<2, 256, 0, stream>>>(W);

    // Fused: acc[n,z] = q^T P q - 2 mu^T P q
    gemm128<0, 0, 1><<<dim3(D / 128, NQ / 128, 2), 256, 0, stream>>>(
        Q, cur, nullptr, nullptr, 1.f, 0.f,
        D, D, D, D, 0, DD, 0, 0, nullptr, W + IDX_U, W + IDX_ACC, Q);

    k_finalize<<<NQ * 2 / 256, 256, 0, stream>>>(W, out);
}

// Round 2
// 2105.677 us; speedup vs baseline: 5.6921x; 5.6921x over previous
//
#include <hip/hip_runtime.h>

#define D   2048
#define S   2048
#define NQ  16384
#define DD  ((long)D * (long)D)

// ---- ws small-region layout (float indices) ----
#define IDX_N      0        // [2] class counts (atomic)
#define IDX_NORMS  16       // [2][16] power-iter norms (atomic)
#define IDX_S      48       // [2] mu^T P mu
#define IDX_SUM    256      // [2][2048] masked column sums (atomic)
#define IDX_MU     4608     // [2][2048] class means
#define IDX_MUF    8704     // [2048]   full mean
#define IDX_U      10752    // [2][2048] u = P mu
#define IDX_V      14848    // [2][2048] power vec ping
#define IDX_W2     18944    // [2][2048] power vec pong
#define IDX_ACC    32768    // [16384][2] logits accumulator (atomic)
#define SMALL_FLOATS 65536  // 256 KB zeroed region

#define NPOW 12
#define NNS  9

typedef unsigned short u16;
typedef __attribute__((ext_vector_type(8))) short short8;
typedef __attribute__((ext_vector_type(4))) short short4v;
typedef __attribute__((ext_vector_type(4))) float f32x4;

__device__ __forceinline__ u16 f2bf(float f) {
    unsigned u = __float_as_uint(f);
    u += 0x7fff + ((u >> 16) & 1);
    return (u16)(u >> 16);
}

__device__ __forceinline__ void gl16(const void* g, void* l) {
    __builtin_amdgcn_global_load_lds((const __attribute__((address_space(1))) void*)g,
                                     (__attribute__((address_space(3))) void*)l, 16, 0, 0);
}

// ---------------- small kernels ----------------

__global__ void k_counts(const int* __restrict__ lab, float* __restrict__ W) {
    int c0 = 0, c1 = 0;
    for (int i = threadIdx.x; i < S; i += 256) {
        int l = lab[i];
        c0 += (l == 0);
        c1 += (l == 1);
    }
    atomicAdd(&W[IDX_N + 0], (float)c0);
    atomicAdd(&W[IDX_N + 1], (float)c1);
}

__global__ void k_colsums(const float* __restrict__ X, const int* __restrict__ lab,
                          float* __restrict__ W) {
    int d  = blockIdx.x * 256 + threadIdx.x;
    int i0 = blockIdx.y * 128;
    float s0 = 0.f, s1 = 0.f;
    for (int i = i0; i < i0 + 128; ++i) {
        float v = X[(long)i * D + d];
        int   l = lab[i];
        s0 += (l == 0) ? v : 0.f;
        s1 += (l == 1) ? v : 0.f;
    }
    atomicAdd(&W[IDX_SUM + d],     s0);
    atomicAdd(&W[IDX_SUM + D + d], s1);
}

__global__ void k_stats(float* __restrict__ W) {
    int d = blockIdx.x * 256 + threadIdx.x;
    float n0 = W[IDX_N], n1 = W[IDX_N + 1];
    float s0 = W[IDX_SUM + d], s1 = W[IDX_SUM + D + d];
    W[IDX_MU + d]     = s0 / n0;
    W[IDX_MU + D + d] = s1 / n1;
    W[IDX_MUF + d]    = (s0 + s1) / (float)S;
    unsigned h = (unsigned)d * 2654435761u;
    float r = 0.5f + (float)((h >> 16) & 1023) / 1024.f;
    W[IDX_V + d]     = r;
    W[IDX_V + D + d] = r;
}

__global__ void k_build_M(float* __restrict__ AM, const float* __restrict__ W) {
    long idx = (long)blockIdx.x * 256 + threadIdx.x;
    int d = (int)(idx / D), e = (int)(idx % D);
    float n0 = W[IDX_N], n1 = W[IDX_N + 1];
    float mufd = W[IDX_MUF + d],     mufe = W[IDX_MUF + e];
    float m0d  = W[IDX_MU + d],      m0e  = W[IDX_MU + e];
    float m1d  = W[IDX_MU + D + d],  m1e  = W[IDX_MU + D + e];
    float a0 = AM[idx], a1 = AM[DD + idx];
    float task = (a0 + a1 - (float)S * mufd * mufe) * (1.f / (float)(S - 1));
    float c0 = (a0 - n0 * m0d * m0e) / (n0 - 1.f);
    float c1 = (a1 - n1 * m1d * m1e) / (n1 - 1.f);
    float l0 = fminf(n0 / (n0 + 1.f), 0.1f);
    float l1 = fminf(n1 / (n1 + 1.f), 0.1f);
    float eye = (d == e) ? 0.1f : 0.f;
    AM[idx]      = l0 * c0 + (1.f - l0) * task + eye;
    AM[DD + idx] = l1 * c1 + (1.f - l1) * task + eye;
}

__global__ void k_pow(const float* __restrict__ Mm, float* __restrict__ W, int it) {
    int z = blockIdx.y;
    const float* Mz = Mm + (long)z * DD;
    float* V  = W + IDX_V  + z * D;
    float* W2 = W + IDX_W2 + z * D;
    const float* in = (it & 1) ? W2 : V;
    float*       out = (it & 1) ? V  : W2;
    float sc = (it > 0) ? rsqrtf(W[IDX_NORMS + z * 16 + it - 1]) : 1.f;
    int wv = threadIdx.x >> 6, ln = threadIdx.x & 63;
    int d = blockIdx.x * 4 + wv;
    float p = 0.f;
    for (int e = ln; e < D; e += 64) p += Mz[(long)d * D + e] * in[e];
    for (int off = 32; off; off >>= 1) p += __shfl_down(p, off);
    if (ln == 0) {
        float w = p * sc;
        out[d] = w;
        atomicAdd(&W[IDX_NORMS + z * 16 + it], w * w);
    }
}

__global__ void k_matvec_u(const float* __restrict__ P, float* __restrict__ W) {
    int z = blockIdx.y;
    const float* Pz = P + (long)z * DD;
    const float* mu = W + IDX_MU + z * D;
    int wv = threadIdx.x >> 6, ln = threadIdx.x & 63;
    int d = blockIdx.x * 4 + wv;
    float p = 0.f;
    for (int e = ln; e < D; e += 64) p += Pz[(long)d * D + e] * mu[e];
    for (int off = 32; off; off >>= 1) p += __shfl_down(p, off);
    if (ln == 0) W[IDX_U + z * D + d] = p;
}

__global__ void k_dot(float* __restrict__ W) {
    int z = blockIdx.x;
    float t = 0.f;
    for (int d = threadIdx.x; d < D; d += 256)
        t += W[IDX_MU + z * D + d] * W[IDX_U + z * D + d];
    for (int off = 32; off; off >>= 1) t += __shfl_down(t, off);
    __shared__ float sm[4];
    int wv = threadIdx.x >> 6, ln = threadIdx.x & 63;
    if (ln == 0) sm[wv] = t;
    __syncthreads();
    if (threadIdx.x == 0) W[IDX_S + z] = sm[0] + sm[1] + sm[2] + sm[3];
}

__global__ void k_finalize(const float* __restrict__ W, float* __restrict__ out) {
    int idx = blockIdx.x * 256 + threadIdx.x;
    int z = idx & 1;
    out[idx] = -(W[IDX_ACC + idx] + W[IDX_S + z]);
}

// ---------------- pack kernels (k-packed bf16 layout: [K/8][cols][8]) ----------------

// support S fp32 [S][D] -> Sp (unmasked) + S0p/S1p (masked) packs
__global__ void k_pack_S(const float* __restrict__ Xs, const int* __restrict__ lab,
                         u16* __restrict__ Sp, u16* __restrict__ S01p) {
    int d = blockIdx.x * 256 + threadIdx.x;
    int a = blockIdx.y;                 // row-group i/8
    short8 p, p0, p1;
#pragma unroll
    for (int j = 0; j < 8; ++j) {
        int i = a * 8 + j;
        float v = Xs[(long)i * D + d];
        int   l = lab[i];
        short b = (short)f2bf(v);
        p[j]  = b;
        p0[j] = (l == 0) ? b : (short)0;
        p1[j] = (l == 1) ? b : (short)0;
    }
    long off = ((long)a * D + d) * 8;
    *(short8*)&Sp[off]        = p;
    *(short8*)&S01p[off]      = p0;
    *(short8*)&S01p[DD + off] = p1;
}

// fp32 [2][D][D] row-major -> bf16 pack [2][D/8][D][8]
__global__ void k_pack_M(const float* __restrict__ Mf, u16* __restrict__ Mp) {
    int c = blockIdx.x * 256 + threadIdx.x;
    int a = blockIdx.y;
    int z = blockIdx.z;
    const float* src = Mf + (long)z * DD;
    u16* dst = Mp + (long)z * DD;
    short8 pk;
#pragma unroll
    for (int j = 0; j < 8; ++j) pk[j] = (short)f2bf(src[(long)(a * 8 + j) * D + c]);
    *(short8*)&dst[((long)a * D + c) * 8] = pk;
}

// Q fp32 [NQ][D] -> pack [D/8][NQ][8]
__global__ void k_pack_Q(const float* __restrict__ Q, u16* __restrict__ Qp) {
    int m = blockIdx.x;
    int t = threadIdx.x;                // k-group
    const float* row = Q + (long)m * D + t * 8;
    float4 v0 = *(const float4*)row;
    float4 v1 = *(const float4*)(row + 4);
    short8 pk;
    pk[0] = (short)f2bf(v0.x); pk[1] = (short)f2bf(v0.y);
    pk[2] = (short)f2bf(v0.z); pk[3] = (short)f2bf(v0.w);
    pk[4] = (short)f2bf(v1.x); pk[5] = (short)f2bf(v1.y);
    pk[6] = (short)f2bf(v1.z); pk[7] = (short)f2bf(v1.w);
    *(short8*)&Qp[((long)t * NQ + m) * 8] = pk;
}

__global__ void k_init_Xf32(float* __restrict__ X, const float* __restrict__ W) {
    int idx = blockIdx.x * 256 + threadIdx.x;   // < 2*DD (fits int)
    int z = idx >= (int)DD;
    int r0 = idx - z * (int)DD;
    int d = r0 / D, e = r0 % D;
    float lam = sqrtf(W[IDX_NORMS + z * 16 + NPOW - 1]);
    float a = 2.f / (0.15f + 1.25f * lam);
    X[idx] = (d == e) ? a : 0.f;
}

__global__ void k_init_Xp(u16* __restrict__ Xp, const float* __restrict__ W) {
    int c = blockIdx.x * 256 + threadIdx.x;
    int a = blockIdx.y;
    int z = blockIdx.z;
    float lam = sqrtf(W[IDX_NORMS + z * 16 + NPOW - 1]);
    u16 ab = f2bf(2.f / (0.15f + 1.25f * lam));
    short8 pk;
#pragma unroll
    for (int j = 0; j < 8; ++j) pk[j] = (a * 8 + j == c) ? (short)ab : (short)0;
    *(short8*)&Xp[(long)z * DD + ((long)a * D + c) * 8] = pk;
}

// ---------------- bf16 MFMA GEMM (128x128 tile, BK=32) ----------------
// Operands are k-packed bf16: pack[k>>3][col][8]. A-use reads the pack as
// A^T (valid: M, X symmetric). EPI: 0 = store fp32 C (Gram);
// 1 = store bf16 pack of (I - acc) (residual R); 2 = X' = Xf32 + acc,
// store fp32 in-place + bf16 pack; 3 = fused logits epilogue.
template <int EPI>
__global__ void __launch_bounds__(256)
bgemm(const u16* __restrict__ Ap, const u16* __restrict__ Bp,
      float* __restrict__ Cf, u16* __restrict__ Cp, float* __restrict__ Ef,
      long sA, long sB, long sCf, long sCp,
      int lda, int K,
      const float* __restrict__ u, float* __restrict__ acc2,
      const float* __restrict__ Qf) {
    int z = blockIdx.z;
    const u16* A = Ap + z * sA;
    const u16* B = Bp + z * sB;

    int n0 = blockIdx.x * 128;
    int m0 = blockIdx.y * 128;
    int tid = threadIdx.x;
    int w = tid >> 6, lane = tid & 63;
    int wr = w >> 1, wc = w & 1;
    int lhi = lane >> 4, llo = lane & 15;

    __shared__ short8 smem8[1024];          // 16 KB: A tile 8K + B tile 8K
    short* Asm = (short*)smem8;             // [4][128][8]
    short* Bsm = Asm + 4096;
    char* AsmB = (char*)Asm;
    char* BsmB = (char*)Bsm;

    f32x4 acc[4][4];
#pragma unroll
    for (int i = 0; i < 4; ++i)
#pragma unroll
        for (int j = 0; j < 4; ++j) acc[i][j] = (f32x4)(0.f);

    for (int k0 = 0; k0 < K; k0 += 32) {
        int kg = (k0 >> 3) + w;             // this wave's k-slab
        const char* gA = (const char*)(A + ((long)kg * lda  + m0) * 8) + lane * 16;
        const char* gB = (const char*)(B + ((long)kg * 2048 + n0) * 8) + lane * 16;
        gl16(gA,        AsmB + w * 2048);
        gl16(gA + 1024, AsmB + w * 2048 + 1024);
        gl16(gB,        BsmB + w * 2048);
        gl16(gB + 1024, BsmB + w * 2048 + 1024);
        __syncthreads();

        short8 af[4], bfr[4];
#pragma unroll
        for (int i = 0; i < 4; ++i)
            af[i] = *(short8*)&Asm[lhi * 1024 + (wr * 64 + i * 16 + llo) * 8];
#pragma unroll
        for (int j = 0; j < 4; ++j)
            bfr[j] = *(short8*)&Bsm[lhi * 1024 + (wc * 64 + j * 16 + llo) * 8];
#pragma unroll
        for (int i = 0; i < 4; ++i)
#pragma unroll
            for (int j = 0; j < 4; ++j)
                acc[i][j] = __builtin_amdgcn_mfma_f32_16x16x32_bf16(af[i], bfr[j], acc[i][j], 0, 0, 0);
        __syncthreads();
    }

    if (EPI == 0) {
        float* C = Cf + z * sCf;
#pragma unroll
        for (int i = 0; i < 4; ++i) {
            int m_b = m0 + wr * 64 + i * 16 + lhi * 4;
#pragma unroll
            for (int j = 0; j < 4; ++j) {
                int n = n0 + wc * 64 + j * 16 + llo;
#pragma unroll
                for (int r = 0; r < 4; ++r)
                    C[(long)(m_b + r) * D + n] = acc[i][j][r];
            }
        }
    } else if (EPI == 1) {
        u16* P = Cp + z * sCp;
#pragma unroll
        for (int i = 0; i < 4; ++i) {
            int m_b = m0 + wr * 64 + i * 16 + lhi * 4;
#pragma unroll
            for (int j = 0; j < 4; ++j) {
                int n = n0 + wc * 64 + j * 16 + llo;
                short4v pk;
#pragma unroll
                for (int r = 0; r < 4; ++r) {
                    float v = ((m_b + r) == n ? 1.f : 0.f) - acc[i][j][r];
                    pk[r] = (short)f2bf(v);
                }
                *(short4v*)((char*)P + ((long)((m_b >> 3) * D + n)) * 16 + (m_b & 7) * 2) = pk;
            }
        }
    } else if (EPI == 2) {
        float* X = Ef + z * DD;
        u16*   P = Cp + z * sCp;
#pragma unroll
        for (int i = 0; i < 4; ++i) {
            int m_b = m0 + wr * 64 + i * 16 + lhi * 4;
#pragma unroll
            for (int j = 0; j < 4; ++j) {
                int n = n0 + wc * 64 + j * 16 + llo;
                short4v pk;
#pragma unroll
                for (int r = 0; r < 4; ++r) {
                    long o = (long)(m_b + r) * D + n;
                    float v = X[o] + acc[i][j][r];
                    X[o] = v;
                    pk[r] = (short)f2bf(v);
                }
                *(short4v*)((char*)P + ((long)((m_b >> 3) * D + n)) * 16 + (m_b & 7) * 2) = pk;
            }
        }
    } else {
        float uv[4];
#pragma unroll
        for (int j = 0; j < 4; ++j) uv[j] = u[z * D + n0 + wc * 64 + j * 16 + llo];
#pragma unroll
        for (int i = 0; i < 4; ++i) {
#pragma unroll
            for (int r = 0; r < 4; ++r) {
                int row = m0 + wr * 64 + i * 16 + lhi * 4 + r;
                float t = 0.f;
#pragma unroll
                for (int j = 0; j < 4; ++j) {
                    int n = n0 + wc * 64 + j * 16 + llo;
                    float qv = Qf[(long)row * D + n];
                    t += (acc[i][j][r] - 2.f * uv[j]) * qv;
                }
                t += __shfl_xor(t, 1);
                t += __shfl_xor(t, 2);
                t += __shfl_xor(t, 4);
                t += __shfl_xor(t, 8);
                if (llo == 0) atomicAdd(&acc2[row * 2 + z], t);
            }
        }
    }
}

// ---------------- launch ----------------

extern "C" void kernel_launch(void* const* d_in, const int* in_sizes, int n_in,
                              void* d_out, int out_size, void* d_ws, size_t ws_size,
                              hipStream_t stream) {
    const float* Q   = (const float*)d_in[0];
    const float* Xs  = (const float*)d_in[1];
    const int*   lab = (const int*)d_in[2];
    float* out = (float*)d_out;
    float* W   = (float*)d_ws;

    char* BIG = (char*)d_ws + (long)SMALL_FLOATS * 4;
    u16*  Sp   = (u16*)(BIG);                    // [S/8][D][8]          8.4 MB
    u16*  S01p = (u16*)(BIG + 8388608L);         // [2][S/8][D][8]      16.8 MB
    u16*  Rp   = (u16*)(BIG + 25165824L);        // [2] pack            16.8 MB
    u16*  Mp   = (u16*)(BIG + 41943040L);        // [2] pack            16.8 MB
    u16*  Xp0  = (u16*)(BIG + 58720256L);        // [2] pack            16.8 MB
    u16*  Xp1  = (u16*)(BIG + 75497472L);        // [2] pack            16.8 MB
    float* F32 = (float*)(BIG + 92274688L);      // [2][D][D] fp32      33.6 MB (Gram->M->X)
    u16*  Qp   = (u16*)(BIG);                    // [D/8][NQ][8] 67 MB, overlays Sp..Xp0 (dead by then)

    hipMemsetAsync(d_ws, 0, SMALL_FLOATS * sizeof(float), stream);

    k_counts<<<1, 256, 0, stream>>>(lab, W);
    k_colsums<<<dim3(D / 256, 16), 256, 0, stream>>>(Xs, lab, W);
    k_stats<<<D / 256, 256, 0, stream>>>(W);
    k_pack_S<<<dim3(D / 256, S / 8), 256, 0, stream>>>(Xs, lab, Sp, S01p);

    // Gram_c = (mask_c S)^T S  -> F32
    bgemm<0><<<dim3(16, 16, 2), 256, 0, stream>>>(
        S01p, Sp, F32, nullptr, nullptr, DD, 0, DD, 0, D, S,
        nullptr, nullptr, nullptr);

    k_build_M<<<(int)(DD / 256), 256, 0, stream>>>(F32, W);

    for (int it = 0; it < NPOW; ++it)
        k_pow<<<dim3(D / 4, 2), 256, 0, stream>>>(F32, W, it);

    k_pack_M<<<dim3(D / 256, D / 8, 2), 256, 0, stream>>>(F32, Mp);

    // X0 = alpha I (overwrites fp32 M; Mp retains bf16 M)
    k_init_Xf32<<<(int)(2 * DD / 256), 256, 0, stream>>>(F32, W);
    k_init_Xp<<<dim3(D / 256, D / 8, 2), 256, 0, stream>>>(Xp0, W);

    u16* xp[2] = {Xp0, Xp1};
    int cur = 0;
    for (int it = 0; it < NNS; ++it) {
        // R = I - M X
        bgemm<1><<<dim3(16, 16, 2), 256, 0, stream>>>(
            Mp, xp[cur], nullptr, Rp, nullptr, DD, DD, 0, DD, D, D,
            nullptr, nullptr, nullptr);
        // X += X^T R  (X symmetric), fp32 in-place + new pack
        bgemm<2><<<dim3(16, 16, 2), 256, 0, stream>>>(
            xp[cur], Rp, nullptr, xp[cur ^ 1], F32, DD, DD, 0, DD, D, D,
            nullptr, nullptr, nullptr);
        cur ^= 1;
    }
    // P: fp32 in F32, bf16 pack in xp[cur] (== Xp1 for NNS=9)

    k_matvec_u<<<dim3(D / 4, 2), 256, 0, stream>>>(F32, W);
    k_dot<<<2, 256, 0, stream>>>(W);

    k_pack_Q<<<NQ, 256, 0, stream>>>(Q, Qp);

    // fused: acc2[n,z] = q^T P q - 2 (P mu)^T q
    bgemm<3><<<dim3(16, 128, 2), 256, 0, stream>>>(
        Qp, xp[cur], nullptr, nullptr, nullptr, 0, DD, 0, 0, NQ, D,
        W + IDX_U, W + IDX_ACC, Q);

    k_finalize<<<NQ * 2 / 256, 256, 0, stream>>>(W, out);
}

// Round 3
// 1531.155 us; speedup vs baseline: 7.8279x; 1.3752x over previous
//
#include <hip/hip_runtime.h>

#define D   2048
#define S   2048
#define NQ  16384
#define DD  ((long)D * (long)D)

// ---- ws small-region layout (float indices) ----
#define IDX_N      0        // [2] class counts (atomic)
#define IDX_NORMS  16       // [2][16] power-iter norms (atomic)
#define IDX_S      48       // [2] mu^T P mu
#define IDX_SUM    256      // [2][2048] masked column sums (atomic)
#define IDX_MU     4608     // [2][2048] class means
#define IDX_MUF    8704     // [2048]   full mean
#define IDX_U      10752    // [2][2048] u = P mu
#define IDX_V      14848    // [2][2048] power vec ping
#define IDX_W2     18944    // [2][2048] power vec pong
#define IDX_ACC    32768    // [16384][2] logits accumulator (atomic)
#define SMALL_FLOATS 65536  // 256 KB zeroed region

#define NPOW 8
#define NNS  5

typedef unsigned short u16;
typedef __attribute__((ext_vector_type(8))) short short8;
typedef __attribute__((ext_vector_type(4))) short short4v;
typedef __attribute__((ext_vector_type(4))) float f32x4;

__device__ __forceinline__ u16 f2bf(float f) {
    unsigned u = __float_as_uint(f);
    u += 0x7fff + ((u >> 16) & 1);
    return (u16)(u >> 16);
}

__device__ __forceinline__ void gl16(const void* g, void* l) {
    __builtin_amdgcn_global_load_lds((const __attribute__((address_space(1))) void*)g,
                                     (__attribute__((address_space(3))) void*)l, 16, 0, 0);
}

// ---------------- small kernels ----------------

__global__ void k_counts(const int* __restrict__ lab, float* __restrict__ W) {
    int c0 = 0, c1 = 0;
    for (int i = threadIdx.x; i < S; i += 256) {
        int l = lab[i];
        c0 += (l == 0);
        c1 += (l == 1);
    }
    atomicAdd(&W[IDX_N + 0], (float)c0);
    atomicAdd(&W[IDX_N + 1], (float)c1);
}

__global__ void k_colsums(const float* __restrict__ X, const int* __restrict__ lab,
                          float* __restrict__ W) {
    int d  = blockIdx.x * 256 + threadIdx.x;
    int i0 = blockIdx.y * 128;
    float s0 = 0.f, s1 = 0.f;
    for (int i = i0; i < i0 + 128; ++i) {
        float v = X[(long)i * D + d];
        int   l = lab[i];
        s0 += (l == 0) ? v : 0.f;
        s1 += (l == 1) ? v : 0.f;
    }
    atomicAdd(&W[IDX_SUM + d],     s0);
    atomicAdd(&W[IDX_SUM + D + d], s1);
}

__global__ void k_stats(float* __restrict__ W) {
    int d = blockIdx.x * 256 + threadIdx.x;
    float n0 = W[IDX_N], n1 = W[IDX_N + 1];
    float s0 = W[IDX_SUM + d], s1 = W[IDX_SUM + D + d];
    W[IDX_MU + d]     = s0 / n0;
    W[IDX_MU + D + d] = s1 / n1;
    W[IDX_MUF + d]    = (s0 + s1) / (float)S;
    unsigned h = (unsigned)d * 2654435761u;
    float r = 0.5f + (float)((h >> 16) & 1023) / 1024.f;
    W[IDX_V + d]     = r;
    W[IDX_V + D + d] = r;
}

__global__ void k_build_M(float* __restrict__ AM, const float* __restrict__ W) {
    long idx = (long)blockIdx.x * 256 + threadIdx.x;
    int d = (int)(idx / D), e = (int)(idx % D);
    float n0 = W[IDX_N], n1 = W[IDX_N + 1];
    float mufd = W[IDX_MUF + d],     mufe = W[IDX_MUF + e];
    float m0d  = W[IDX_MU + d],      m0e  = W[IDX_MU + e];
    float m1d  = W[IDX_MU + D + d],  m1e  = W[IDX_MU + D + e];
    float a0 = AM[idx], a1 = AM[DD + idx];
    float task = (a0 + a1 - (float)S * mufd * mufe) * (1.f / (float)(S - 1));
    float c0 = (a0 - n0 * m0d * m0e) / (n0 - 1.f);
    float c1 = (a1 - n1 * m1d * m1e) / (n1 - 1.f);
    float l0 = fminf(n0 / (n0 + 1.f), 0.1f);
    float l1 = fminf(n1 / (n1 + 1.f), 0.1f);
    float eye = (d == e) ? 0.1f : 0.f;
    AM[idx]      = l0 * c0 + (1.f - l0) * task + eye;
    AM[DD + idx] = l1 * c1 + (1.f - l1) * task + eye;
}

__global__ void k_pow(const float* __restrict__ Mm, float* __restrict__ W, int it) {
    int z = blockIdx.y;
    const float* Mz = Mm + (long)z * DD;
    float* V  = W + IDX_V  + z * D;
    float* W2 = W + IDX_W2 + z * D;
    const float* in = (it & 1) ? W2 : V;
    float*       out = (it & 1) ? V  : W2;
    float sc = (it > 0) ? rsqrtf(W[IDX_NORMS + z * 16 + it - 1]) : 1.f;
    int wv = threadIdx.x >> 6, ln = threadIdx.x & 63;
    int d = blockIdx.x * 4 + wv;
    float p = 0.f;
    for (int e = ln; e < D; e += 64) p += Mz[(long)d * D + e] * in[e];
    for (int off = 32; off; off >>= 1) p += __shfl_down(p, off);
    if (ln == 0) {
        float w = p * sc;
        out[d] = w;
        atomicAdd(&W[IDX_NORMS + z * 16 + it], w * w);
    }
}

__global__ void k_matvec_u(const float* __restrict__ P, float* __restrict__ W) {
    int z = blockIdx.y;
    const float* Pz = P + (long)z * DD;
    const float* mu = W + IDX_MU + z * D;
    int wv = threadIdx.x >> 6, ln = threadIdx.x & 63;
    int d = blockIdx.x * 4 + wv;
    float p = 0.f;
    for (int e = ln; e < D; e += 64) p += Pz[(long)d * D + e] * mu[e];
    for (int off = 32; off; off >>= 1) p += __shfl_down(p, off);
    if (ln == 0) W[IDX_U + z * D + d] = p;
}

__global__ void k_dot(float* __restrict__ W) {
    int z = blockIdx.x;
    float t = 0.f;
    for (int d = threadIdx.x; d < D; d += 256)
        t += W[IDX_MU + z * D + d] * W[IDX_U + z * D + d];
    for (int off = 32; off; off >>= 1) t += __shfl_down(t, off);
    __shared__ float sm[4];
    int wv = threadIdx.x >> 6, ln = threadIdx.x & 63;
    if (ln == 0) sm[wv] = t;
    __syncthreads();
    if (threadIdx.x == 0) W[IDX_S + z] = sm[0] + sm[1] + sm[2] + sm[3];
}

__global__ void k_finalize(const float* __restrict__ W, float* __restrict__ out) {
    int idx = blockIdx.x * 256 + threadIdx.x;
    int z = idx & 1;
    out[idx] = -(W[IDX_ACC + idx] + W[IDX_S + z]);
}

// ---------------- pack kernels (k-packed bf16 layout: [K/8][cols][8]) ----------------

__global__ void k_pack_S(const float* __restrict__ Xs, const int* __restrict__ lab,
                         u16* __restrict__ Sp, u16* __restrict__ S01p) {
    int d = blockIdx.x * 256 + threadIdx.x;
    int a = blockIdx.y;                 // row-group i/8
    short8 p, p0, p1;
#pragma unroll
    for (int j = 0; j < 8; ++j) {
        int i = a * 8 + j;
        float v = Xs[(long)i * D + d];
        int   l = lab[i];
        short b = (short)f2bf(v);
        p[j]  = b;
        p0[j] = (l == 0) ? b : (short)0;
        p1[j] = (l == 1) ? b : (short)0;
    }
    long off = ((long)a * D + d) * 8;
    *(short8*)&Sp[off]        = p;
    *(short8*)&S01p[off]      = p0;
    *(short8*)&S01p[DD + off] = p1;
}

__global__ void k_pack_M(const float* __restrict__ Mf, u16* __restrict__ Mp) {
    int c = blockIdx.x * 256 + threadIdx.x;
    int a = blockIdx.y;
    int z = blockIdx.z;
    const float* src = Mf + (long)z * DD;
    u16* dst = Mp + (long)z * DD;
    short8 pk;
#pragma unroll
    for (int j = 0; j < 8; ++j) pk[j] = (short)f2bf(src[(long)(a * 8 + j) * D + c]);
    *(short8*)&dst[((long)a * D + c) * 8] = pk;
}

__global__ void k_pack_Q(const float* __restrict__ Q, u16* __restrict__ Qp) {
    int m = blockIdx.x;
    int t = threadIdx.x;                // k-group
    const float* row = Q + (long)m * D + t * 8;
    float4 v0 = *(const float4*)row;
    float4 v1 = *(const float4*)(row + 4);
    short8 pk;
    pk[0] = (short)f2bf(v0.x); pk[1] = (short)f2bf(v0.y);
    pk[2] = (short)f2bf(v0.z); pk[3] = (short)f2bf(v0.w);
    pk[4] = (short)f2bf(v1.x); pk[5] = (short)f2bf(v1.y);
    pk[6] = (short)f2bf(v1.z); pk[7] = (short)f2bf(v1.w);
    *(short8*)&Qp[((long)t * NQ + m) * 8] = pk;
}

// ---------------- bf16 MFMA GEMM (128x128 tile, BK=32) ----------------
// Operands are k-packed bf16: pack[k>>3][col][8]. A-use reads the pack as
// A^T (valid: M, X symmetric). EPI: 0 = store fp32 C (Gram);
// 1 = store bf16 pack of (I - acc) (residual R); 2 = X' = Xf32 + acc,
// store fp32 in-place + bf16 pack; 3 = fused logits epilogue;
// 4 = Chebyshev init: X0 = C0*I + C1*Mf32 + C2*acc (acc = M^2),
//     fp32 in-place over Mf32 + bf16 pack (coeffs from lambda_max in u=W+NORMS).
template <int EPI>
__global__ void __launch_bounds__(256)
bgemm(const u16* __restrict__ Ap, const u16* __restrict__ Bp,
      float* __restrict__ Cf, u16* __restrict__ Cp, float* __restrict__ Ef,
      long sA, long sB, long sCf, long sCp,
      int lda, int K,
      const float* __restrict__ u, float* __restrict__ acc2,
      const float* __restrict__ Qf) {
    int z = blockIdx.z;
    const u16* A = Ap + z * sA;
    const u16* B = Bp + z * sB;

    int n0 = blockIdx.x * 128;
    int m0 = blockIdx.y * 128;
    int tid = threadIdx.x;
    int w = tid >> 6, lane = tid & 63;
    int wr = w >> 1, wc = w & 1;
    int lhi = lane >> 4, llo = lane & 15;

    __shared__ short8 smem8[1024];          // 16 KB: A tile 8K + B tile 8K
    short* Asm = (short*)smem8;             // [4][128][8]
    short* Bsm = Asm + 4096;
    char* AsmB = (char*)Asm;
    char* BsmB = (char*)Bsm;

    f32x4 acc[4][4];
#pragma unroll
    for (int i = 0; i < 4; ++i)
#pragma unroll
        for (int j = 0; j < 4; ++j) acc[i][j] = (f32x4)(0.f);

    for (int k0 = 0; k0 < K; k0 += 32) {
        int kg = (k0 >> 3) + w;             // this wave's k-slab
        const char* gA = (const char*)(A + ((long)kg * lda  + m0) * 8) + lane * 16;
        const char* gB = (const char*)(B + ((long)kg * 2048 + n0) * 8) + lane * 16;
        gl16(gA,        AsmB + w * 2048);
        gl16(gA + 1024, AsmB + w * 2048 + 1024);
        gl16(gB,        BsmB + w * 2048);
        gl16(gB + 1024, BsmB + w * 2048 + 1024);
        __syncthreads();

        short8 af[4], bfr[4];
#pragma unroll
        for (int i = 0; i < 4; ++i)
            af[i] = *(short8*)&Asm[lhi * 1024 + (wr * 64 + i * 16 + llo) * 8];
#pragma unroll
        for (int j = 0; j < 4; ++j)
            bfr[j] = *(short8*)&Bsm[lhi * 1024 + (wc * 64 + j * 16 + llo) * 8];
#pragma unroll
        for (int i = 0; i < 4; ++i)
#pragma unroll
            for (int j = 0; j < 4; ++j)
                acc[i][j] = __builtin_amdgcn_mfma_f32_16x16x32_bf16(af[i], bfr[j], acc[i][j], 0, 0, 0);
        __syncthreads();
    }

    if (EPI == 0) {
        float* C = Cf + z * sCf;
#pragma unroll
        for (int i = 0; i < 4; ++i) {
            int m_b = m0 + wr * 64 + i * 16 + lhi * 4;
#pragma unroll
            for (int j = 0; j < 4; ++j) {
                int n = n0 + wc * 64 + j * 16 + llo;
#pragma unroll
                for (int r = 0; r < 4; ++r)
                    C[(long)(m_b + r) * D + n] = acc[i][j][r];
            }
        }
    } else if (EPI == 1) {
        u16* P = Cp + z * sCp;
#pragma unroll
        for (int i = 0; i < 4; ++i) {
            int m_b = m0 + wr * 64 + i * 16 + lhi * 4;
#pragma unroll
            for (int j = 0; j < 4; ++j) {
                int n = n0 + wc * 64 + j * 16 + llo;
                short4v pk;
#pragma unroll
                for (int r = 0; r < 4; ++r) {
                    float v = ((m_b + r) == n ? 1.f : 0.f) - acc[i][j][r];
                    pk[r] = (short)f2bf(v);
                }
                *(short4v*)((char*)P + ((long)((m_b >> 3) * D + n)) * 16 + (m_b & 7) * 2) = pk;
            }
        }
    } else if (EPI == 2) {
        float* X = Ef + z * DD;
        u16*   P = Cp + z * sCp;
#pragma unroll
        for (int i = 0; i < 4; ++i) {
            int m_b = m0 + wr * 64 + i * 16 + lhi * 4;
#pragma unroll
            for (int j = 0; j < 4; ++j) {
                int n = n0 + wc * 64 + j * 16 + llo;
                short4v pk;
#pragma unroll
                for (int r = 0; r < 4; ++r) {
                    long o = (long)(m_b + r) * D + n;
                    float v = X[o] + acc[i][j][r];
                    X[o] = v;
                    pk[r] = (short)f2bf(v);
                }
                *(short4v*)((char*)P + ((long)((m_b >> 3) * D + n)) * 16 + (m_b & 7) * 2) = pk;
            }
        }
    } else if (EPI == 4) {
        // Chebyshev degree-3 minimax init for 1/x on [aa, bb]:
        // q(x) = 1 - T3(phi(x))/T3(phi(0)), X0 = p(M) = C0 I + C1 M + C2 M^2
        float lam = sqrtf(u[z * 16 + NPOW - 1]);
        float bb = 1.25f * lam + 0.05f, aa = 0.095f;
        float als = 2.f / (bb - aa);
        float bet = -(bb + aa) / (bb - aa);
        float t3  = (4.f * bet * bet - 3.f) * bet;
        float C2 = -4.f * als * als * als / t3;
        float C1 = -12.f * als * als * bet / t3;
        float C0 = -als * (12.f * bet * bet - 3.f) / t3;
        float* Xf = Ef + z * DD;   // holds fp32 M in, X0 out
        u16*   P  = Cp + z * sCp;
#pragma unroll
        for (int i = 0; i < 4; ++i) {
            int m_b = m0 + wr * 64 + i * 16 + lhi * 4;
#pragma unroll
            for (int j = 0; j < 4; ++j) {
                int n = n0 + wc * 64 + j * 16 + llo;
                short4v pk;
#pragma unroll
                for (int r = 0; r < 4; ++r) {
                    long o = (long)(m_b + r) * D + n;
                    float eye = ((m_b + r) == n) ? 1.f : 0.f;
                    float v = C0 * eye + C1 * Xf[o] + C2 * acc[i][j][r];
                    Xf[o] = v;
                    pk[r] = (short)f2bf(v);
                }
                *(short4v*)((char*)P + ((long)((m_b >> 3) * D + n)) * 16 + (m_b & 7) * 2) = pk;
            }
        }
    } else {
        float uv[4];
#pragma unroll
        for (int j = 0; j < 4; ++j) uv[j] = u[z * D + n0 + wc * 64 + j * 16 + llo];
#pragma unroll
        for (int i = 0; i < 4; ++i) {
#pragma unroll
            for (int r = 0; r < 4; ++r) {
                int row = m0 + wr * 64 + i * 16 + lhi * 4 + r;
                float t = 0.f;
#pragma unroll
                for (int j = 0; j < 4; ++j) {
                    int n = n0 + wc * 64 + j * 16 + llo;
                    float qv = Qf[(long)row * D + n];
                    t += (acc[i][j][r] - 2.f * uv[j]) * qv;
                }
                t += __shfl_xor(t, 1);
                t += __shfl_xor(t, 2);
                t += __shfl_xor(t, 4);
                t += __shfl_xor(t, 8);
                if (llo == 0) atomicAdd(&acc2[row * 2 + z], t);
            }
        }
    }
}

// ---------------- launch ----------------

extern "C" void kernel_launch(void* const* d_in, const int* in_sizes, int n_in,
                              void* d_out, int out_size, void* d_ws, size_t ws_size,
                              hipStream_t stream) {
    const float* Q   = (const float*)d_in[0];
    const float* Xs  = (const float*)d_in[1];
    const int*   lab = (const int*)d_in[2];
    float* out = (float*)d_out;
    float* W   = (float*)d_ws;

    char* BIG = (char*)d_ws + (long)SMALL_FLOATS * 4;
    u16*  Sp   = (u16*)(BIG);                    // [S/8][D][8]          8.4 MB
    u16*  S01p = (u16*)(BIG + 8388608L);         // [2][S/8][D][8]      16.8 MB
    u16*  Rp   = (u16*)(BIG + 25165824L);        // [2] pack            16.8 MB
    u16*  Mp   = (u16*)(BIG + 41943040L);        // [2] pack            16.8 MB
    u16*  Xp0  = (u16*)(BIG + 58720256L);        // [2] pack            16.8 MB
    u16*  Xp1  = (u16*)(BIG + 75497472L);        // [2] pack            16.8 MB
    float* F32 = (float*)(BIG + 92274688L);      // [2][D][D] fp32      33.6 MB (Gram->M->X)
    u16*  Qp   = (u16*)(BIG);                    // [D/8][NQ][8] 67 MB, overlays Sp..Xp0-front (dead then)

    hipMemsetAsync(d_ws, 0, SMALL_FLOATS * sizeof(float), stream);

    k_counts<<<1, 256, 0, stream>>>(lab, W);
    k_colsums<<<dim3(D / 256, 16), 256, 0, stream>>>(Xs, lab, W);
    k_stats<<<D / 256, 256, 0, stream>>>(W);
    k_pack_S<<<dim3(D / 256, S / 8), 256, 0, stream>>>(Xs, lab, Sp, S01p);

    // Gram_c = (mask_c S)^T S  -> F32
    bgemm<0><<<dim3(16, 16, 2), 256, 0, stream>>>(
        S01p, Sp, F32, nullptr, nullptr, DD, 0, DD, 0, D, S,
        nullptr, nullptr, nullptr);

    k_build_M<<<(int)(DD / 256), 256, 0, stream>>>(F32, W);

    for (int it = 0; it < NPOW; ++it)
        k_pow<<<dim3(D / 4, 2), 256, 0, stream>>>(F32, W, it);

    k_pack_M<<<dim3(D / 256, D / 8, 2), 256, 0, stream>>>(F32, Mp);

    // X0 = C0 I + C1 M + C2 M^2 (Chebyshev deg-3 init): one GEMM (M^2) + fused epilogue.
    // Overwrites fp32 M in F32 with X0; writes bf16 pack to Xp0. Mp keeps bf16 M.
    bgemm<4><<<dim3(16, 16, 2), 256, 0, stream>>>(
        Mp, Mp, nullptr, Xp0, F32, DD, DD, 0, DD, D, D,
        W + IDX_NORMS, nullptr, nullptr);

    u16* xp[2] = {Xp0, Xp1};
    int cur = 0;
    for (int it = 0; it < NNS; ++it) {
        // R = I - M X
        bgemm<1><<<dim3(16, 16, 2), 256, 0, stream>>>(
            Mp, xp[cur], nullptr, Rp, nullptr, DD, DD, 0, DD, D, D,
            nullptr, nullptr, nullptr);
        // X += X^T R  (X symmetric), fp32 in-place + new pack
        bgemm<2><<<dim3(16, 16, 2), 256, 0, stream>>>(
            xp[cur], Rp, nullptr, xp[cur ^ 1], F32, DD, DD, 0, DD, D, D,
            nullptr, nullptr, nullptr);
        cur ^= 1;
    }
    // P: fp32 in F32, bf16 pack in xp[cur] (== Xp1 for odd NNS)

    k_matvec_u<<<dim3(D / 4, 2), 256, 0, stream>>>(F32, W);
    k_dot<<<2, 256, 0, stream>>>(W);

    k_pack_Q<<<NQ, 256, 0, stream>>>(Q, Qp);

    // fused: acc2[n,z] = q^T P q - 2 (P mu)^T q
    bgemm<3><<<dim3(16, 128, 2), 256, 0, stream>>>(
        Qp, xp[cur], nullptr, nullptr, nullptr, 0, DD, 0, 0, NQ, D,
        W + IDX_U, W + IDX_ACC, Q);

    k_finalize<<<NQ * 2 / 256, 256, 0, stream>>>(W, out);
}